// Round 2
// baseline (4451.986 us; speedup 1.0000x reference)
//
#include <hip/hip_runtime.h>
#include <hip/hip_bf16.h>

// ---------------------------------------------------------------------------
// SimpleGCN: 4x GCNConv(128->128, ELU) + mean pool (64 graphs) + linear (->10)
// N=100000 nodes, E=1.6M edges, F=H=128.
// Strategy v1 (correctness-first, fp32 end-to-end):
//   - deg/dinv/norm computed once (shared across layers)
//   - per layer: tiled GEMM (ELU fused on input load), scatter-init (self loop
//     + bias fused), edge-parallel atomicAdd scatter
//   - pooling via atomics (8192 dst addrs, plenty of parallelism), tiny final GEMM
// ---------------------------------------------------------------------------

#define FDIM 128

__device__ __forceinline__ float elu_f(float v) {
    return v > 0.0f ? v : expf(v) - 1.0f;
}

// ---------------- graph-normalization precompute ----------------

__global__ __launch_bounds__(256) void k_deg_init(float* __restrict__ deg, int n) {
    int i = blockIdx.x * 256 + threadIdx.x;
    if (i < n) deg[i] = 1.0f;  // self-loop weight
}

__global__ __launch_bounds__(256) void k_deg_acc(const int* __restrict__ dst,
                                                 const float* __restrict__ ew,
                                                 float* __restrict__ deg, int e) {
    int i = blockIdx.x * 256 + threadIdx.x;
    if (i < e) atomicAdd(&deg[dst[i]], ew[i]);
}

__global__ __launch_bounds__(256) void k_dinv(const float* __restrict__ deg,
                                              float* __restrict__ dinv, int n) {
    int i = blockIdx.x * 256 + threadIdx.x;
    if (i < n) dinv[i] = rsqrtf(deg[i]);  // deg >= 1 always
}

__global__ __launch_bounds__(256) void k_norm(const int* __restrict__ src,
                                              const int* __restrict__ dst,
                                              const float* __restrict__ ew,
                                              const float* __restrict__ dinv,
                                              float* __restrict__ nrm, int e) {
    int i = blockIdx.x * 256 + threadIdx.x;
    if (i < e) nrm[i] = dinv[src[i]] * ew[i] * dinv[dst[i]];
}

// ---------------- dense GEMM: H = act(X) @ W  (K=128, Ncol=128) -------------
// block: 256 threads, tile 128 rows x 128 cols, per-thread 8x8 register tile.

template <bool ELU>
__global__ __launch_bounds__(256) void k_gemm(const float* __restrict__ X,
                                              const float* __restrict__ W,
                                              float* __restrict__ H, int n) {
    __shared__ float xs[32][129];  // transposed chunk: xs[k][row]
    __shared__ float wsm[32][128]; // wsm[k][col]
    const int tid = threadIdx.x;
    const int row0 = blockIdx.x * 128;
    const int cg = tid & 15;   // -> cols cg*8 .. cg*8+7
    const int rg = tid >> 4;   // -> rows rg*8 .. rg*8+7

    float acc[8][8];
#pragma unroll
    for (int i = 0; i < 8; ++i)
#pragma unroll
        for (int j = 0; j < 8; ++j) acc[i][j] = 0.0f;

    for (int k0 = 0; k0 < 128; k0 += 32) {
        // stage X chunk (transposed), apply ELU on load if requested
        {
            const int kk = tid & 31;
            for (int rr = (tid >> 5); rr < 128; rr += 8) {
                int gr = row0 + rr;
                float v = 0.0f;
                if (gr < n) v = X[(size_t)gr * FDIM + k0 + kk];
                if (ELU) v = elu_f(v);
                xs[kk][rr] = v;
            }
        }
        // stage W chunk
        for (int i = tid; i < 32 * 128; i += 256) {
            int kk = i >> 7, cc = i & 127;
            wsm[kk][cc] = W[(size_t)(k0 + kk) * FDIM + cc];
        }
        __syncthreads();

#pragma unroll
        for (int k = 0; k < 32; ++k) {
            float xv[8], wv[8];
#pragma unroll
            for (int i = 0; i < 8; ++i) xv[i] = xs[k][rg * 8 + i];
#pragma unroll
            for (int j = 0; j < 8; ++j) wv[j] = wsm[k][cg * 8 + j];
#pragma unroll
            for (int i = 0; i < 8; ++i)
#pragma unroll
                for (int j = 0; j < 8; ++j) acc[i][j] += xv[i] * wv[j];
        }
        __syncthreads();
    }

#pragma unroll
    for (int i = 0; i < 8; ++i) {
        int gr = row0 + rg * 8 + i;
        if (gr < n) {
            float4* p = (float4*)&H[(size_t)gr * FDIM + cg * 8];
            p[0] = make_float4(acc[i][0], acc[i][1], acc[i][2], acc[i][3]);
            p[1] = make_float4(acc[i][4], acc[i][5], acc[i][6], acc[i][7]);
        }
    }
}

// ---------------- scatter: A = selfloop + bias, then += norm * H[src] -------

__global__ __launch_bounds__(256) void k_scatter_init(const float* __restrict__ Hm,
                                                      const float* __restrict__ dinv,
                                                      const float* __restrict__ bias,
                                                      float* __restrict__ A, int n) {
    int idx = blockIdx.x * 256 + threadIdx.x;
    if (idx < n * FDIM) {
        int node = idx >> 7, f = idx & 127;
        float di = dinv[node];
        A[idx] = di * di * Hm[idx] + bias[f];
    }
}

// one wave per edge; 2 features per lane
__global__ __launch_bounds__(256) void k_scatter_edges(const float* __restrict__ Hm,
                                                       const int* __restrict__ src,
                                                       const int* __restrict__ dst,
                                                       const float* __restrict__ nrm,
                                                       float* __restrict__ A, int e) {
    int wid = (blockIdx.x * 256 + threadIdx.x) >> 6;
    int lane = threadIdx.x & 63;
    if (wid >= e) return;
    int s = src[wid], d = dst[wid];
    float w = nrm[wid];
    float v0 = Hm[(size_t)s * FDIM + lane];
    float v1 = Hm[(size_t)s * FDIM + 64 + lane];
    atomicAdd(&A[(size_t)d * FDIM + lane], w * v0);
    atomicAdd(&A[(size_t)d * FDIM + 64 + lane], w * v1);
}

// ---------------- pooling + final linear ----------------

__global__ __launch_bounds__(256) void k_pool(const float* __restrict__ A,
                                              const int* __restrict__ batch,
                                              float* __restrict__ pooled,
                                              float* __restrict__ cnt, int n) {
    int wid = (blockIdx.x * 256 + threadIdx.x) >> 6;
    int lane = threadIdx.x & 63;
    if (wid >= n) return;
    int g = batch[wid];
    float v0 = elu_f(A[(size_t)wid * FDIM + lane]);
    float v1 = elu_f(A[(size_t)wid * FDIM + 64 + lane]);
    atomicAdd(&pooled[g * FDIM + lane], v0);
    atomicAdd(&pooled[g * FDIM + 64 + lane], v1);
    if (lane == 0) atomicAdd(&cnt[g], 1.0f);
}

__global__ __launch_bounds__(256) void k_final(const float* __restrict__ pooled,
                                               const float* __restrict__ cnt,
                                               const float* __restrict__ Wlin,
                                               const float* __restrict__ blin,
                                               float* __restrict__ out, int G, int C) {
    int idx = blockIdx.x * 256 + threadIdx.x;
    if (idx >= G * C) return;
    int g = idx / C, c = idx % C;
    float inv = 1.0f / fmaxf(cnt[g], 1.0f);
    float acc = 0.0f;
    for (int k = 0; k < FDIM; ++k) acc += pooled[g * FDIM + k] * Wlin[k * C + c];
    out[idx] = acc * inv + blin[c];
}

// ---------------------------------------------------------------------------

extern "C" void kernel_launch(void* const* d_in, const int* in_sizes, int n_in,
                              void* d_out, int out_size, void* d_ws, size_t ws_size,
                              hipStream_t stream) {
    const float* x         = (const float*)d_in[0];
    const int*   edge_idx  = (const int*)d_in[1];
    const float* edge_attr = (const float*)d_in[2];
    // d_in[3] edge_type: unused by reference
    const int*   batch     = (const int*)d_in[4];
    const float* Wl[4] = {(const float*)d_in[5], (const float*)d_in[7],
                          (const float*)d_in[9], (const float*)d_in[11]};
    const float* bl[4] = {(const float*)d_in[6], (const float*)d_in[8],
                          (const float*)d_in[10], (const float*)d_in[12]};
    const float* Wlin = (const float*)d_in[13];
    const float* blin = (const float*)d_in[14];
    float* out = (float*)d_out;

    const int N = in_sizes[0] / FDIM;
    const int E = in_sizes[2];       // edge_attr is (E,1)
    const int C = in_sizes[14];      // blin
    const int G = out_size / C;

    const int* src = edge_idx;
    const int* dst = edge_idx + E;

    // workspace layout (floats)
    float* ws   = (float*)d_ws;
    float* deg  = ws;                       // N
    float* dinv = deg + N;                  // N
    float* nrm  = dinv + N;                 // E
    float* h    = nrm + E;                  // N*128
    float* a    = h + (size_t)N * FDIM;     // N*128
    float* pooled = a + (size_t)N * FDIM;   // G*128
    float* cnt  = pooled + (size_t)G * FDIM; // G

    const int B = 256;

    // graph normalization (once; shared by all 4 layers)
    k_deg_init<<<(N + B - 1) / B, B, 0, stream>>>(deg, N);
    k_deg_acc<<<(E + B - 1) / B, B, 0, stream>>>(dst, edge_attr, deg, E);
    k_dinv<<<(N + B - 1) / B, B, 0, stream>>>(deg, dinv, N);
    k_norm<<<(E + B - 1) / B, B, 0, stream>>>(src, dst, edge_attr, dinv, nrm, E);

    const int gemm_grid = (N + 127) / 128;
    const long scatter_grid = ((long)E * 64 + B - 1) / B;
    const int init_grid = ((long)N * FDIM + B - 1) / B;
    const long pool_grid = ((long)N * 64 + B - 1) / B;

    for (int l = 0; l < 4; ++l) {
        if (l == 0)
            k_gemm<false><<<gemm_grid, B, 0, stream>>>(x, Wl[l], h, N);
        else
            k_gemm<true><<<gemm_grid, B, 0, stream>>>(a, Wl[l], h, N);
        k_scatter_init<<<init_grid, B, 0, stream>>>(h, dinv, bl[l], a, N);
        k_scatter_edges<<<(int)scatter_grid, B, 0, stream>>>(h, src, dst, nrm, a, E);
    }

    // pooling
    hipMemsetAsync(pooled, 0, ((size_t)G * FDIM + G) * sizeof(float), stream);
    k_pool<<<(int)pool_grid, B, 0, stream>>>(a, batch, pooled, cnt, N);
    k_final<<<(G * C + B - 1) / B, B, 0, stream>>>(pooled, cnt, Wlin, blin, out, G, C);
}

// Round 3
// 1739.209 us; speedup vs baseline: 2.5598x; 2.5598x over previous
//
#include <hip/hip_runtime.h>
#include <hip/hip_bf16.h>

// ---------------------------------------------------------------------------
// SimpleGCN v2: kill the atomic sinks.
//  - CSR by dst built once per call (count -> scan -> fill), shared by 4 layers
//  - k_aggregate: wave-per-node gather, register accumulate, NO atomics,
//    self-loop + bias fused (replaces scatter_init + scatter_edges)
//  - k_pool2: sorted-batch segmented reduction, flush-on-boundary atomics only
//  - GEMM unchanged (fp32 required by 3.25e-5 threshold; no fp32 MFMA on CDNA4)
// ---------------------------------------------------------------------------

#define FDIM 128

__device__ __forceinline__ float elu_f(float v) {
    return v > 0.0f ? v : expf(v) - 1.0f;
}

// ---------------- init: deg=1 (self loop), cnt=0 ----------------

__global__ __launch_bounds__(256) void k_init(float* __restrict__ deg,
                                              int* __restrict__ cnt, int n) {
    int i = blockIdx.x * 256 + threadIdx.x;
    if (i < n) { deg[i] = 1.0f; cnt[i] = 0; }
}

__global__ __launch_bounds__(256) void k_deg_cnt(const int* __restrict__ dst,
                                                 const float* __restrict__ ew,
                                                 float* __restrict__ deg,
                                                 int* __restrict__ cnt, int e) {
    int i = blockIdx.x * 256 + threadIdx.x;
    if (i < e) {
        int d = dst[i];
        atomicAdd(&deg[d], ew[i]);
        atomicAdd(&cnt[d], 1);
    }
}

__global__ __launch_bounds__(256) void k_dinv(const float* __restrict__ deg,
                                              float* __restrict__ dinv, int n) {
    int i = blockIdx.x * 256 + threadIdx.x;
    if (i < n) dinv[i] = rsqrtf(deg[i]);  // deg >= 1 always
}

// ---------------- exclusive scan of cnt -> row_ptr (3 kernels) ----------------

__global__ __launch_bounds__(256) void k_scan1(const int* __restrict__ cnt,
                                               int* __restrict__ row_ptr,
                                               int* __restrict__ aux, int n) {
    __shared__ int sh[256];
    int t = threadIdx.x;
    int i = blockIdx.x * 256 + t;
    int v = (i < n) ? cnt[i] : 0;
    sh[t] = v;
    __syncthreads();
    for (int off = 1; off < 256; off <<= 1) {
        int x = (t >= off) ? sh[t - off] : 0;
        __syncthreads();
        sh[t] += x;
        __syncthreads();
    }
    if (i < n) row_ptr[i] = sh[t] - v;      // exclusive within block
    if (t == 255) aux[blockIdx.x] = sh[255]; // block total
}

__global__ __launch_bounds__(256) void k_scan2(int* __restrict__ aux, int nblocks) {
    __shared__ int sh[256];
    __shared__ int carry_s;
    int t = threadIdx.x;
    if (t == 0) carry_s = 0;
    __syncthreads();
    for (int base = 0; base < nblocks; base += 256) {
        int i = base + t;
        int v = (i < nblocks) ? aux[i] : 0;
        sh[t] = v;
        __syncthreads();
        for (int off = 1; off < 256; off <<= 1) {
            int x = (t >= off) ? sh[t - off] : 0;
            __syncthreads();
            sh[t] += x;
            __syncthreads();
        }
        int carry = carry_s;
        if (i < nblocks) aux[i] = carry + sh[t] - v;  // exclusive across blocks
        __syncthreads();
        if (t == 255) carry_s = carry + sh[255];
        __syncthreads();
    }
}

__global__ __launch_bounds__(256) void k_scan3(int* __restrict__ row_ptr,
                                               const int* __restrict__ aux,
                                               int* __restrict__ cnt,
                                               int n, int e_total) {
    int i = blockIdx.x * 256 + threadIdx.x;
    if (i < n) {
        row_ptr[i] += aux[blockIdx.x];
        cnt[i] = 0;  // reuse as fill cursor
    }
    if (i == 0) row_ptr[n] = e_total;
}

// ---------------- fill CSR (nrm fused) ----------------

__global__ __launch_bounds__(256) void k_fill(const int* __restrict__ src,
                                              const int* __restrict__ dst,
                                              const float* __restrict__ ew,
                                              const float* __restrict__ dinv,
                                              const int* __restrict__ row_ptr,
                                              int* __restrict__ cursor,
                                              int* __restrict__ src_sorted,
                                              float* __restrict__ nrm_sorted, int e) {
    int i = blockIdx.x * 256 + threadIdx.x;
    if (i >= e) return;
    int d = dst[i], s = src[i];
    int pos = row_ptr[d] + atomicAdd(&cursor[d], 1);
    src_sorted[pos] = s;
    nrm_sorted[pos] = dinv[s] * ew[i] * dinv[d];
}

// ---------------- dense GEMM: H = act(X) @ W  (K=128, Ncol=128) -------------

template <bool ELU>
__global__ __launch_bounds__(256) void k_gemm(const float* __restrict__ X,
                                              const float* __restrict__ W,
                                              float* __restrict__ H, int n) {
    __shared__ float xs[32][129];  // transposed chunk: xs[k][row]
    __shared__ float wsm[32][128]; // wsm[k][col]
    const int tid = threadIdx.x;
    const int row0 = blockIdx.x * 128;
    const int cg = tid & 15;
    const int rg = tid >> 4;

    float acc[8][8];
#pragma unroll
    for (int i = 0; i < 8; ++i)
#pragma unroll
        for (int j = 0; j < 8; ++j) acc[i][j] = 0.0f;

    for (int k0 = 0; k0 < 128; k0 += 32) {
        {
            const int kk = tid & 31;
            for (int rr = (tid >> 5); rr < 128; rr += 8) {
                int gr = row0 + rr;
                float v = 0.0f;
                if (gr < n) v = X[(size_t)gr * FDIM + k0 + kk];
                if (ELU) v = elu_f(v);
                xs[kk][rr] = v;
            }
        }
        for (int i = tid; i < 32 * 128; i += 256) {
            int kk = i >> 7, cc = i & 127;
            wsm[kk][cc] = W[(size_t)(k0 + kk) * FDIM + cc];
        }
        __syncthreads();

#pragma unroll
        for (int k = 0; k < 32; ++k) {
            float xv[8], wv[8];
#pragma unroll
            for (int i = 0; i < 8; ++i) xv[i] = xs[k][rg * 8 + i];
#pragma unroll
            for (int j = 0; j < 8; ++j) wv[j] = wsm[k][cg * 8 + j];
#pragma unroll
            for (int i = 0; i < 8; ++i)
#pragma unroll
                for (int j = 0; j < 8; ++j) acc[i][j] += xv[i] * wv[j];
        }
        __syncthreads();
    }

#pragma unroll
    for (int i = 0; i < 8; ++i) {
        int gr = row0 + rg * 8 + i;
        if (gr < n) {
            float4* p = (float4*)&H[(size_t)gr * FDIM + cg * 8];
            p[0] = make_float4(acc[i][0], acc[i][1], acc[i][2], acc[i][3]);
            p[1] = make_float4(acc[i][4], acc[i][5], acc[i][6], acc[i][7]);
        }
    }
}

// ---------------- aggregate: A[d] = dinv[d]^2*H[d] + bias + sum_in nrm*H[s] --
// one wave per dst node, 2 features per lane, register accumulate, no atomics

__global__ __launch_bounds__(256) void k_aggregate(const float* __restrict__ H,
                                                   const int* __restrict__ row_ptr,
                                                   const int* __restrict__ src_sorted,
                                                   const float* __restrict__ nrm_sorted,
                                                   const float* __restrict__ dinv,
                                                   const float* __restrict__ bias,
                                                   float* __restrict__ A, int n) {
    int node = (blockIdx.x * 256 + threadIdx.x) >> 6;
    int lane = threadIdx.x & 63;
    if (node >= n) return;
    int r0 = row_ptr[node], r1 = row_ptr[node + 1];
    float di = dinv[node];
    float acc0 = di * di * H[(size_t)node * FDIM + lane] + bias[lane];
    float acc1 = di * di * H[(size_t)node * FDIM + 64 + lane] + bias[64 + lane];

    int e = r0;
    for (; e + 1 < r1; e += 2) {
        int s0 = src_sorted[e], s1 = src_sorted[e + 1];
        float w0 = nrm_sorted[e], w1 = nrm_sorted[e + 1];
        float x0 = H[(size_t)s0 * FDIM + lane];
        float x1 = H[(size_t)s0 * FDIM + 64 + lane];
        float y0 = H[(size_t)s1 * FDIM + lane];
        float y1 = H[(size_t)s1 * FDIM + 64 + lane];
        acc0 += w0 * x0;
        acc1 += w0 * x1;
        acc0 += w1 * y0;
        acc1 += w1 * y1;
    }
    if (e < r1) {
        int s0 = src_sorted[e];
        float w0 = nrm_sorted[e];
        acc0 += w0 * H[(size_t)s0 * FDIM + lane];
        acc1 += w0 * H[(size_t)s0 * FDIM + 64 + lane];
    }
    A[(size_t)node * FDIM + lane] = acc0;
    A[(size_t)node * FDIM + 64 + lane] = acc1;
}

// ---------------- pooling: sorted-batch segmented reduction ----------------
// wave owns a 64-node contiguous chunk; flush atomics only on graph change.

#define POOL_CH 64

__global__ __launch_bounds__(256) void k_pool2(const float* __restrict__ A,
                                               const int* __restrict__ batch,
                                               float* __restrict__ pooled,
                                               float* __restrict__ cntf, int n) {
    int wave = (blockIdx.x * 256 + threadIdx.x) >> 6;
    int lane = threadIdx.x & 63;
    int start = wave * POOL_CH;
    if (start >= n) return;
    int end = min(start + POOL_CH, n);

    float a0 = 0.0f, a1 = 0.0f;
    int c = 0;
    int gcur = batch[start];
    for (int i = start; i < end; ++i) {
        int g = batch[i];  // wave-uniform
        if (g != gcur) {
            atomicAdd(&pooled[gcur * FDIM + lane], a0);
            atomicAdd(&pooled[gcur * FDIM + 64 + lane], a1);
            if (lane == 0) atomicAdd(&cntf[gcur], (float)c);
            a0 = a1 = 0.0f; c = 0; gcur = g;
        }
        a0 += elu_f(A[(size_t)i * FDIM + lane]);
        a1 += elu_f(A[(size_t)i * FDIM + 64 + lane]);
        ++c;
    }
    atomicAdd(&pooled[gcur * FDIM + lane], a0);
    atomicAdd(&pooled[gcur * FDIM + 64 + lane], a1);
    if (lane == 0) atomicAdd(&cntf[gcur], (float)c);
}

__global__ __launch_bounds__(256) void k_final(const float* __restrict__ pooled,
                                               const float* __restrict__ cntf,
                                               const float* __restrict__ Wlin,
                                               const float* __restrict__ blin,
                                               float* __restrict__ out, int G, int C) {
    int idx = blockIdx.x * 256 + threadIdx.x;
    if (idx >= G * C) return;
    int g = idx / C, c = idx % C;
    float inv = 1.0f / fmaxf(cntf[g], 1.0f);
    float acc = 0.0f;
    for (int k = 0; k < FDIM; ++k) acc += pooled[g * FDIM + k] * Wlin[k * C + c];
    out[idx] = acc * inv + blin[c];
}

// ---------------------------------------------------------------------------

extern "C" void kernel_launch(void* const* d_in, const int* in_sizes, int n_in,
                              void* d_out, int out_size, void* d_ws, size_t ws_size,
                              hipStream_t stream) {
    const float* x         = (const float*)d_in[0];
    const int*   edge_idx  = (const int*)d_in[1];
    const float* edge_attr = (const float*)d_in[2];
    const int*   batch     = (const int*)d_in[4];
    const float* Wl[4] = {(const float*)d_in[5], (const float*)d_in[7],
                          (const float*)d_in[9], (const float*)d_in[11]};
    const float* bl[4] = {(const float*)d_in[6], (const float*)d_in[8],
                          (const float*)d_in[10], (const float*)d_in[12]};
    const float* Wlin = (const float*)d_in[13];
    const float* blin = (const float*)d_in[14];
    float* out = (float*)d_out;

    const int N = in_sizes[0] / FDIM;
    const int E = in_sizes[2];       // edge_attr is (E,1)
    const int C = in_sizes[14];      // blin
    const int G = out_size / C;

    const int* src = edge_idx;
    const int* dst = edge_idx + E;

    // workspace layout (4-byte units)
    char* wsb = (char*)d_ws;
    size_t off = 0;
    auto alloc = [&](size_t elems) { void* p = wsb + off; off += elems * 4; return p; };
    float* deg        = (float*)alloc(N);
    float* dinv       = (float*)alloc(N);
    int*   cnt        = (int*)alloc(N);
    int*   row_ptr    = (int*)alloc(N + 1);
    int*   aux        = (int*)alloc(4096);
    int*   src_sorted = (int*)alloc(E);
    float* nrm_sorted = (float*)alloc(E);
    float* h          = (float*)alloc((size_t)N * FDIM);
    float* a          = (float*)alloc((size_t)N * FDIM);
    float* pooled     = (float*)alloc((size_t)G * FDIM);
    float* cntf       = (float*)alloc(G);

    const int B = 256;
    const int nb_n = (N + B - 1) / B;      // node-grid blocks
    const int nb_e = (E + B - 1) / B;      // edge-grid blocks

    // ---- CSR + normalization (once, shared by all 4 layers) ----
    k_init<<<nb_n, B, 0, stream>>>(deg, cnt, N);
    k_deg_cnt<<<nb_e, B, 0, stream>>>(dst, edge_attr, deg, cnt, E);
    k_dinv<<<nb_n, B, 0, stream>>>(deg, dinv, N);
    k_scan1<<<nb_n, B, 0, stream>>>(cnt, row_ptr, aux, N);
    k_scan2<<<1, B, 0, stream>>>(aux, nb_n);
    k_scan3<<<nb_n, B, 0, stream>>>(row_ptr, aux, cnt, N, E);
    k_fill<<<nb_e, B, 0, stream>>>(src, dst, edge_attr, dinv, row_ptr, cnt,
                                   src_sorted, nrm_sorted, E);

    // ---- 4 GCN layers ----
    const int gemm_grid = (N + 127) / 128;
    const int agg_grid = (int)(((size_t)N * 64 + B - 1) / B);
    for (int l = 0; l < 4; ++l) {
        if (l == 0)
            k_gemm<false><<<gemm_grid, B, 0, stream>>>(x, Wl[l], h, N);
        else
            k_gemm<true><<<gemm_grid, B, 0, stream>>>(a, Wl[l], h, N);
        k_aggregate<<<agg_grid, B, 0, stream>>>(h, row_ptr, src_sorted, nrm_sorted,
                                                dinv, bl[l], a, N);
    }

    // ---- pooling + final linear ----
    hipMemsetAsync(pooled, 0, ((size_t)G * FDIM + G) * sizeof(float), stream);
    const int pool_waves = (N + POOL_CH - 1) / POOL_CH;
    const int pool_grid = (pool_waves * 64 + B - 1) / B;
    k_pool2<<<pool_grid, B, 0, stream>>>(a, batch, pooled, cntf, N);
    k_final<<<(G * C + B - 1) / B, B, 0, stream>>>(pooled, cntf, Wlin, blin, out, G, C);
}

// Round 10
// 1247.015 us; speedup vs baseline: 3.5701x; 1.3947x over previous
//
#include <hip/hip_runtime.h>
#include <hip/hip_bf16.h>

// ---------------------------------------------------------------------------
// SimpleGCN v5:
//  - GEMM: exact fp32 VALU, vectorized (float4 LDS reads, ds_read_b128),
//    transposed-X staging, unroll-4 k-loop. MFMA split-bf16 route abandoned:
//    v3 (2-way) and v4 (3-way) both landed ~1.5e-3 absmax — correction passes
//    empirically don't correct on gfx950; threshold needs exact fp32.
//  - aggregate: (node, feature-half) per wave + 4x unrolled gather (no atomics)
//  - CSR by dst built once per call; pool via sorted-batch segmented reduction
// ---------------------------------------------------------------------------

#define FDIM 128

__device__ __forceinline__ float elu_f(float v) {
    return v > 0.0f ? v : expf(v) - 1.0f;
}

// ---------------- graph-normalization precompute ----------------

__global__ __launch_bounds__(256) void k_init(float* __restrict__ deg,
                                              int* __restrict__ cnt, int n) {
    int i = blockIdx.x * 256 + threadIdx.x;
    if (i < n) { deg[i] = 1.0f; cnt[i] = 0; }
}

__global__ __launch_bounds__(256) void k_deg_cnt(const int* __restrict__ dst,
                                                 const float* __restrict__ ew,
                                                 float* __restrict__ deg,
                                                 int* __restrict__ cnt, int e) {
    int i = blockIdx.x * 256 + threadIdx.x;
    if (i < e) {
        int d = dst[i];
        atomicAdd(&deg[d], ew[i]);
        atomicAdd(&cnt[d], 1);
    }
}

__global__ __launch_bounds__(256) void k_dinv(const float* __restrict__ deg,
                                              float* __restrict__ dinv, int n) {
    int i = blockIdx.x * 256 + threadIdx.x;
    if (i < n) dinv[i] = rsqrtf(deg[i]);
}

// ---------------- exclusive scan of cnt -> row_ptr ----------------

__global__ __launch_bounds__(256) void k_scan1(const int* __restrict__ cnt,
                                               int* __restrict__ row_ptr,
                                               int* __restrict__ aux, int n) {
    __shared__ int sh[256];
    int t = threadIdx.x;
    int i = blockIdx.x * 256 + t;
    int v = (i < n) ? cnt[i] : 0;
    sh[t] = v;
    __syncthreads();
    for (int off = 1; off < 256; off <<= 1) {
        int x = (t >= off) ? sh[t - off] : 0;
        __syncthreads();
        sh[t] += x;
        __syncthreads();
    }
    if (i < n) row_ptr[i] = sh[t] - v;
    if (t == 255) aux[blockIdx.x] = sh[255];
}

__global__ __launch_bounds__(256) void k_scan2(int* __restrict__ aux, int nblocks) {
    __shared__ int sh[256];
    __shared__ int carry_s;
    int t = threadIdx.x;
    if (t == 0) carry_s = 0;
    __syncthreads();
    for (int base = 0; base < nblocks; base += 256) {
        int i = base + t;
        int v = (i < nblocks) ? aux[i] : 0;
        sh[t] = v;
        __syncthreads();
        for (int off = 1; off < 256; off <<= 1) {
            int x = (t >= off) ? sh[t - off] : 0;
            __syncthreads();
            sh[t] += x;
            __syncthreads();
        }
        int carry = carry_s;
        if (i < nblocks) aux[i] = carry + sh[t] - v;
        __syncthreads();
        if (t == 255) carry_s = carry + sh[255];
        __syncthreads();
    }
}

__global__ __launch_bounds__(256) void k_scan3(int* __restrict__ row_ptr,
                                               const int* __restrict__ aux,
                                               int* __restrict__ cnt,
                                               int n, int e_total) {
    int i = blockIdx.x * 256 + threadIdx.x;
    if (i < n) {
        row_ptr[i] += aux[blockIdx.x];
        cnt[i] = 0;
    }
    if (i == 0) row_ptr[n] = e_total;
}

__global__ __launch_bounds__(256) void k_fill(const int* __restrict__ src,
                                              const int* __restrict__ dst,
                                              const float* __restrict__ ew,
                                              const float* __restrict__ dinv,
                                              const int* __restrict__ row_ptr,
                                              int* __restrict__ cursor,
                                              int* __restrict__ src_sorted,
                                              float* __restrict__ nrm_sorted, int e) {
    int i = blockIdx.x * 256 + threadIdx.x;
    if (i >= e) return;
    int d = dst[i], s = src[i];
    int pos = row_ptr[d] + atomicAdd(&cursor[d], 1);
    src_sorted[pos] = s;
    nrm_sorted[pos] = dinv[s] * ew[i] * dinv[d];
}

// ---------------- dense GEMM: H = act(X) @ W  (exact fp32, vectorized) -----
// block 256 thr; tile 128 rows x 128 cols; per-thread 8x8; K chunks of 32.
// xs[k][row] (transposed), ws[k][col]; inner loop reads 4x float4 per k-step.

template <bool ELU>
__global__ __launch_bounds__(256) void k_gemm32(const float* __restrict__ X,
                                                const float* __restrict__ W,
                                                float* __restrict__ H, int n) {
    __shared__ float xs[32][132];  // [k][row], pad 4 floats (16B-aligned rows)
    __shared__ float ws[32][132];  // [k][col]
    const int tid  = threadIdx.x;
    const int row0 = blockIdx.x * 128;
    const int cg   = tid & 15;     // col group -> cols cg*8..+7
    const int rg   = tid >> 4;     // row group -> rows rg*8..+7

    float acc[8][8];
#pragma unroll
    for (int i = 0; i < 8; ++i)
#pragma unroll
        for (int j = 0; j < 8; ++j) acc[i][j] = 0.0f;

    for (int k0 = 0; k0 < 128; k0 += 32) {
        // ---- stage X^T: thread t -> row r = t&127, k-half kh = t>>7 (16 k) ----
        {
            const int r  = tid & 127;
            const int kh = tid >> 7;               // 0 or 1
            const int gr = row0 + r;
            float4 v[4];
#pragma unroll
            for (int q = 0; q < 4; ++q) {
                v[q] = make_float4(0.f, 0.f, 0.f, 0.f);
                if (gr < n)
                    v[q] = *(const float4*)&X[(size_t)gr * FDIM + k0 + kh * 16 + q * 4];
                if (ELU) {
                    v[q].x = elu_f(v[q].x); v[q].y = elu_f(v[q].y);
                    v[q].z = elu_f(v[q].z); v[q].w = elu_f(v[q].w);
                }
            }
#pragma unroll
            for (int q = 0; q < 4; ++q) {
                xs[kh * 16 + q * 4 + 0][r] = v[q].x;
                xs[kh * 16 + q * 4 + 1][r] = v[q].y;
                xs[kh * 16 + q * 4 + 2][r] = v[q].z;
                xs[kh * 16 + q * 4 + 3][r] = v[q].w;
            }
        }
        // ---- stage W: thread t -> k = t>>3, col chunk (t&7)*16 ----
        {
            const int k  = tid >> 3;               // 0..31
            const int c0 = (tid & 7) * 16;         // 0..112
#pragma unroll
            for (int q = 0; q < 4; ++q) {
                float4 wv = *(const float4*)&W[(size_t)(k0 + k) * FDIM + c0 + q * 4];
                *(float4*)&ws[k][c0 + q * 4] = wv;
            }
        }
        __syncthreads();

#pragma unroll 4
        for (int k = 0; k < 32; ++k) {
            float4 xv0 = *(const float4*)&xs[k][rg * 8];
            float4 xv1 = *(const float4*)&xs[k][rg * 8 + 4];
            float4 wv0 = *(const float4*)&ws[k][cg * 8];
            float4 wv1 = *(const float4*)&ws[k][cg * 8 + 4];
            float xv[8] = {xv0.x, xv0.y, xv0.z, xv0.w, xv1.x, xv1.y, xv1.z, xv1.w};
            float wv[8] = {wv0.x, wv0.y, wv0.z, wv0.w, wv1.x, wv1.y, wv1.z, wv1.w};
#pragma unroll
            for (int i = 0; i < 8; ++i)
#pragma unroll
                for (int j = 0; j < 8; ++j)
                    acc[i][j] = fmaf(xv[i], wv[j], acc[i][j]);
        }
        __syncthreads();
    }

#pragma unroll
    for (int i = 0; i < 8; ++i) {
        int gr = row0 + rg * 8 + i;
        if (gr < n) {
            float4* p = (float4*)&H[(size_t)gr * FDIM + cg * 8];
            p[0] = make_float4(acc[i][0], acc[i][1], acc[i][2], acc[i][3]);
            p[1] = make_float4(acc[i][4], acc[i][5], acc[i][6], acc[i][7]);
        }
    }
}

// ---------------- aggregate: (node, half) per wave, 4x unrolled gather ------

__global__ __launch_bounds__(256) void k_aggregate2(const float* __restrict__ H,
                                                    const int* __restrict__ row_ptr,
                                                    const int* __restrict__ srcs,
                                                    const float* __restrict__ nrms,
                                                    const float* __restrict__ dinv,
                                                    const float* __restrict__ bias,
                                                    float* __restrict__ A, int n) {
    int gw   = (blockIdx.x * 256 + threadIdx.x) >> 6;
    int lane = threadIdx.x & 63;
    int node = gw >> 1;
    int f    = ((gw & 1) << 6) + lane;
    if (node >= n) return;
    int r0 = row_ptr[node], r1 = row_ptr[node + 1];
    float di = dinv[node];
    float acc = di * di * H[(size_t)node * FDIM + f] + bias[f];

    int e = r0;
    for (; e + 4 <= r1; e += 4) {
        int   s0 = srcs[e],     s1 = srcs[e + 1], s2 = srcs[e + 2], s3 = srcs[e + 3];
        float w0 = nrms[e],     w1 = nrms[e + 1], w2 = nrms[e + 2], w3 = nrms[e + 3];
        float v0 = H[(size_t)s0 * FDIM + f];
        float v1 = H[(size_t)s1 * FDIM + f];
        float v2 = H[(size_t)s2 * FDIM + f];
        float v3 = H[(size_t)s3 * FDIM + f];
        acc = fmaf(w0, v0, acc);
        acc = fmaf(w1, v1, acc);
        acc = fmaf(w2, v2, acc);
        acc = fmaf(w3, v3, acc);
    }
    for (; e < r1; ++e)
        acc = fmaf(nrms[e], H[(size_t)srcs[e] * FDIM + f], acc);

    A[(size_t)node * FDIM + f] = acc;
}

// ---------------- pooling + final linear ----------------

#define POOL_CH 64

__global__ __launch_bounds__(256) void k_pool2(const float* __restrict__ A,
                                               const int* __restrict__ batch,
                                               float* __restrict__ pooled,
                                               float* __restrict__ cntf, int n) {
    int wave = (blockIdx.x * 256 + threadIdx.x) >> 6;
    int lane = threadIdx.x & 63;
    int start = wave * POOL_CH;
    if (start >= n) return;
    int end = min(start + POOL_CH, n);

    float a0 = 0.0f, a1 = 0.0f;
    int c = 0;
    int gcur = batch[start];
    for (int i = start; i < end; ++i) {
        int g = batch[i];
        if (g != gcur) {
            atomicAdd(&pooled[gcur * FDIM + lane], a0);
            atomicAdd(&pooled[gcur * FDIM + 64 + lane], a1);
            if (lane == 0) atomicAdd(&cntf[gcur], (float)c);
            a0 = a1 = 0.0f; c = 0; gcur = g;
        }
        a0 += elu_f(A[(size_t)i * FDIM + lane]);
        a1 += elu_f(A[(size_t)i * FDIM + 64 + lane]);
        ++c;
    }
    atomicAdd(&pooled[gcur * FDIM + lane], a0);
    atomicAdd(&pooled[gcur * FDIM + 64 + lane], a1);
    if (lane == 0) atomicAdd(&cntf[gcur], (float)c);
}

__global__ __launch_bounds__(256) void k_final(const float* __restrict__ pooled,
                                               const float* __restrict__ cntf,
                                               const float* __restrict__ Wlin,
                                               const float* __restrict__ blin,
                                               float* __restrict__ out, int G, int C) {
    int idx = blockIdx.x * 256 + threadIdx.x;
    if (idx >= G * C) return;
    int g = idx / C, c = idx % C;
    float inv = 1.0f / fmaxf(cntf[g], 1.0f);
    float acc = 0.0f;
    for (int k = 0; k < FDIM; ++k) acc += pooled[g * FDIM + k] * Wlin[k * C + c];
    out[idx] = acc * inv + blin[c];
}

// ---------------------------------------------------------------------------

extern "C" void kernel_launch(void* const* d_in, const int* in_sizes, int n_in,
                              void* d_out, int out_size, void* d_ws, size_t ws_size,
                              hipStream_t stream) {
    const float* x         = (const float*)d_in[0];
    const int*   edge_idx  = (const int*)d_in[1];
    const float* edge_attr = (const float*)d_in[2];
    const int*   batch     = (const int*)d_in[4];
    const float* Wl[4] = {(const float*)d_in[5], (const float*)d_in[7],
                          (const float*)d_in[9], (const float*)d_in[11]};
    const float* bl[4] = {(const float*)d_in[6], (const float*)d_in[8],
                          (const float*)d_in[10], (const float*)d_in[12]};
    const float* Wlin = (const float*)d_in[13];
    const float* blin = (const float*)d_in[14];
    float* out = (float*)d_out;

    const int N = in_sizes[0] / FDIM;
    const int E = in_sizes[2];
    const int C = in_sizes[14];
    const int G = out_size / C;

    const int* src = edge_idx;
    const int* dst = edge_idx + E;

    // workspace layout (4-byte units)
    char* wsb = (char*)d_ws;
    size_t off = 0;
    auto alloc = [&](size_t elems) { void* p = wsb + off; off += elems * 4; return p; };
    float*  deg        = (float*)alloc(N);
    float*  dinv       = (float*)alloc(N);
    int*    cnt        = (int*)alloc(N);
    int*    row_ptr    = (int*)alloc(N + 1);
    int*    aux        = (int*)alloc(4096);
    int*    src_sorted = (int*)alloc(E);
    float*  nrm_sorted = (float*)alloc(E);
    float*  h          = (float*)alloc((size_t)N * FDIM);
    float*  a          = (float*)alloc((size_t)N * FDIM);
    float*  pooled     = (float*)alloc((size_t)G * FDIM);
    float*  cntf       = (float*)alloc(G);

    const int B = 256;
    const int nb_n = (N + B - 1) / B;
    const int nb_e = (E + B - 1) / B;

    // ---- CSR + normalization (shared precompute) ----
    k_init<<<nb_n, B, 0, stream>>>(deg, cnt, N);
    k_deg_cnt<<<nb_e, B, 0, stream>>>(dst, edge_attr, deg, cnt, E);
    k_dinv<<<nb_n, B, 0, stream>>>(deg, dinv, N);
    k_scan1<<<nb_n, B, 0, stream>>>(cnt, row_ptr, aux, N);
    k_scan2<<<1, B, 0, stream>>>(aux, nb_n);
    k_scan3<<<nb_n, B, 0, stream>>>(row_ptr, aux, cnt, N, E);
    k_fill<<<nb_e, B, 0, stream>>>(src, dst, edge_attr, dinv, row_ptr, cnt,
                                   src_sorted, nrm_sorted, E);

    // ---- 4 GCN layers ----
    const int gemm_grid = (N + 127) / 128;
    const int agg_grid  = (int)(((size_t)N * 2 * 64 + B - 1) / B);
    for (int l = 0; l < 4; ++l) {
        if (l == 0)
            k_gemm32<false><<<gemm_grid, B, 0, stream>>>(x, Wl[l], h, N);
        else
            k_gemm32<true><<<gemm_grid, B, 0, stream>>>(a, Wl[l], h, N);
        k_aggregate2<<<agg_grid, B, 0, stream>>>(h, row_ptr, src_sorted, nrm_sorted,
                                                 dinv, bl[l], a, N);
    }

    // ---- pooling + final linear ----
    hipMemsetAsync(pooled, 0, ((size_t)G * FDIM + G) * sizeof(float), stream);
    const int pool_waves = (N + POOL_CH - 1) / POOL_CH;
    const int pool_grid = (pool_waves * 64 + B - 1) / B;
    k_pool2<<<pool_grid, B, 0, stream>>>(a, batch, pooled, cntf, N);
    k_final<<<(G * C + B - 1) / B, B, 0, stream>>>(pooled, cntf, Wlin, blin, out, G, C);
}